// Round 2
// baseline (812.805 us; speedup 1.0000x reference)
//
#include <hip/hip_runtime.h>
#include <math.h>
#include <float.h>
#include <limits.h>

#define N 8192
#define D 64
#define TOPK 32

// ---------------------------------------------------------------------------
// Kernel 1: row norms of X1 and X2 -> ws[0..2N)
// ---------------------------------------------------------------------------
__global__ __launch_bounds__(256) void norms_kernel(
    const float* __restrict__ X1, const float* __restrict__ X2,
    float* __restrict__ nrm)
{
    int id = blockIdx.x * blockDim.x + threadIdx.x;
    if (id >= 2 * N) return;
    const float* X = (id < N) ? X1 : X2;
    int r = (id < N) ? id : id - N;
    const float4* p = (const float4*)(X + (size_t)r * D);
    float s = 0.f;
#pragma unroll
    for (int q = 0; q < D / 4; ++q) {
        float4 v = p[q];
        s += v.x * v.x + v.y * v.y + v.z * v.z + v.w * v.w;
    }
    nrm[id] = s;
}

// ---------------------------------------------------------------------------
// Kernel 2: neg_dist -> out (dense). 128x128 tile / block, 8x8 per thread.
// LDS layout: As[d][col'] with col' = r ^ 8*((d>>2)&7)  (XOR swizzle keeps
// b128 reads 16B-aligned & conflict-free at LDA=128 -> exactly 64 KB LDS).
// Thread cols are {4tx..4tx+3} and {64+4tx..}, rows {8ty..8ty+7}.
// ---------------------------------------------------------------------------
#define TILE 128

__global__ __launch_bounds__(256, 2) void dist_kernel(
    const float* __restrict__ X1, const float* __restrict__ X2,
    const float* __restrict__ nrm, float* __restrict__ out)
{
    __shared__ float As[D * TILE];
    __shared__ float Bs[D * TILE];

    const int t = threadIdx.x;
    const int row0 = blockIdx.y * TILE;
    const int col0 = blockIdx.x * TILE;

    // stage both tiles, transposed + swizzled
#pragma unroll
    for (int p = 0; p < 8; ++p) {
        int lin = p * 256 + t;          // 0..2047
        int r   = lin >> 4;             // 0..127
        int d4  = (lin & 15) << 2;      // 0,4,...,60
        int g   = (d4 >> 2) & 7;        // same for d4..d4+3
        int cb  = r ^ (g << 3);
        float4 a = *(const float4*)(X1 + (size_t)(row0 + r) * D + d4);
        As[(d4 + 0) * TILE + cb] = a.x;
        As[(d4 + 1) * TILE + cb] = a.y;
        As[(d4 + 2) * TILE + cb] = a.z;
        As[(d4 + 3) * TILE + cb] = a.w;
        float4 b = *(const float4*)(X2 + (size_t)(col0 + r) * D + d4);
        Bs[(d4 + 0) * TILE + cb] = b.x;
        Bs[(d4 + 1) * TILE + cb] = b.y;
        Bs[(d4 + 2) * TILE + cb] = b.z;
        Bs[(d4 + 3) * TILE + cb] = b.w;
    }
    __syncthreads();

    const int tx = t & 15;
    const int ty = t >> 4;
    float acc[8][8] = {};

#pragma unroll 8
    for (int k = 0; k < D; ++k) {
        int gk  = (k >> 2) & 7;
        int ab  = k * TILE + ((ty ^ gk) << 3);
        int bb0 = k * TILE + ((4 * tx) ^ (gk << 3));
        float4 a0 = *(const float4*)&As[ab];
        float4 a1 = *(const float4*)&As[ab + 4];
        float4 b0 = *(const float4*)&Bs[bb0];
        float4 b1 = *(const float4*)&Bs[bb0 + 64];
        float av[8] = {a0.x, a0.y, a0.z, a0.w, a1.x, a1.y, a1.z, a1.w};
        float bv[8] = {b0.x, b0.y, b0.z, b0.w, b1.x, b1.y, b1.z, b1.w};
#pragma unroll
        for (int i = 0; i < 8; ++i)
#pragma unroll
            for (int j = 0; j < 8; ++j)
                acc[i][j] += av[i] * bv[j];
    }

    float na[8], nb[8];
#pragma unroll
    for (int i = 0; i < 8; ++i) na[i] = nrm[row0 + 8 * ty + i];
#pragma unroll
    for (int q = 0; q < 4; ++q) {
        nb[q]     = nrm[N + col0 + 4 * tx + q];
        nb[4 + q] = nrm[N + col0 + 64 + 4 * tx + q];
    }

#pragma unroll
    for (int i = 0; i < 8; ++i) {
        float* po = out + (size_t)(row0 + 8 * ty + i) * N + col0 + 4 * tx;
        float4 o0, o1;
        float* f0 = (float*)&o0;
        float* f1 = (float*)&o1;
#pragma unroll
        for (int q = 0; q < 4; ++q) {
            float s0 = na[i] + nb[q] - 2.0f * acc[i][q];
            f0[q] = -sqrtf(fmaxf(s0, 0.0f));
            float s1 = na[i] + nb[4 + q] - 2.0f * acc[i][4 + q];
            f1[q] = -sqrtf(fmaxf(s1, 0.0f));
        }
        *(float4*)po        = o0;
        *(float4*)(po + 64) = o1;
    }
}

// ---------------------------------------------------------------------------
// Kernel 3: one WAVE per row. thr = min-of-lane-maxes (sound: >=64 survivors,
// 32nd-best >= thr). Compact survivors to per-wave LDS, register-resident
// 32x argmax via shfl (tie: value desc, index asc), softmax, zero + scatter.
// No __syncthreads in the selection loop; one barrier after compaction.
// ---------------------------------------------------------------------------
#define CAP 2016   // 63*32; per-lane <= 32 strided slots; 63 KB LDS total

__global__ __launch_bounds__(256) void topk_kernel(
    float* __restrict__ out, float* __restrict__ score_out)
{
    __shared__ float cand_v[4][CAP];
    __shared__ int   cand_j[4][CAP];

    const int t    = threadIdx.x;
    const int w    = t >> 6;
    const int lane = t & 63;
    const int r    = blockIdx.x * 4 + w;
    float* row = out + (size_t)r * N;

    // load 128 values per lane (coalesced float4)
    float v[128];
#pragma unroll
    for (int c = 0; c < 32; ++c) {
        float4 x = ((const float4*)row)[c * 64 + lane];
        v[4 * c + 0] = x.x; v[4 * c + 1] = x.y;
        v[4 * c + 2] = x.z; v[4 * c + 3] = x.w;
    }
    // col of v[u]: 4*((u>>2)*64 + lane) + (u&3)

    // thr = wave-min of per-lane maxes (each lane has >=1 survivor)
    float m = v[0];
#pragma unroll
    for (int u = 1; u < 128; ++u) m = fmaxf(m, v[u]);
    float thr = m;
    for (int off = 32; off > 0; off >>= 1) thr = fminf(thr, __shfl_xor(thr, off));

    // compact survivors (v >= thr) into per-wave LDS via wave prefix sum
    int myc = 0;
#pragma unroll
    for (int u = 0; u < 128; ++u) myc += (v[u] >= thr) ? 1 : 0;
    int sum = myc;
    for (int off = 1; off < 64; off <<= 1) {
        int y = __shfl_up(sum, off);
        if (lane >= off) sum += y;
    }
    const int total = __shfl(sum, 63);
    int p = sum - myc;
#pragma unroll
    for (int u = 0; u < 128; ++u) {
        if (v[u] >= thr) {
            if (p < CAP) {
                cand_v[w][p] = v[u];
                cand_j[w][p] = 4 * ((u >> 2) * 64 + lane) + (u & 3);
            }
            ++p;
        }
    }
    const int cnt = (total < CAP) ? total : CAP;
    __syncthreads();   // LDS visibility across lanes (uniform flow)

    // strided re-read into registers: lane owns slots i*64+lane
    float lv[32]; int lj[32];
    const int kmax = (cnt + 63) >> 6;   // wave-uniform
#pragma unroll
    for (int i = 0; i < 32; ++i) { lv[i] = -FLT_MAX; lj[i] = INT_MAX; }
#pragma unroll
    for (int i = 0; i < 32; ++i) {
        if (i >= kmax) break;
        int q = i * 64 + lane;
        if (q < cnt) { lv[i] = cand_v[w][q]; lj[i] = cand_j[w][q]; }
    }

    // 32 x wave argmax, pure registers + shfl
    float myv = -FLT_MAX; int myj = 0;
    for (int it = 0; it < TOPK; ++it) {
        float bv = -FLT_MAX; int bj = INT_MAX; int bi = 0;
#pragma unroll
        for (int i = 0; i < 32; ++i) {
            if (i >= kmax) break;
            if (lv[i] > bv || (lv[i] == bv && lj[i] < bj)) { bv = lv[i]; bj = lj[i]; bi = i; }
        }
        int bpos = (bi << 6) | lane;
        for (int off = 32; off > 0; off >>= 1) {
            float ov = __shfl_down(bv, off);
            int   oj = __shfl_down(bj, off);
            int   op = __shfl_down(bpos, off);
            if (ov > bv || (ov == bv && oj < bj)) { bv = ov; bj = oj; bpos = op; }
        }
        float bv0 = __shfl(bv, 0);
        int   bj0 = __shfl(bj, 0);
        int   bp0 = __shfl(bpos, 0);
        if (lane == (bp0 & 63)) {
            int bi0 = bp0 >> 6;
#pragma unroll
            for (int i = 0; i < 32; ++i) if (i == bi0) lv[i] = -FLT_MAX;
        }
        if (lane == it) { myv = bv0; myj = bj0; }
    }

    // softmax over the 32 selected (rank == lane)
    float Mx = __shfl(myv, 0);
    float e  = (lane < TOPK) ? expf(myv - Mx) : 0.f;
    float Z  = e;
    for (int off = 32; off > 0; off >>= 1) Z += __shfl_xor(Z, off);
    float s = e / Z;
    if (lane < TOPK) score_out[(size_t)r * TOPK + lane] = s;

    // zero the row (all loads already consumed), then scatter
    const float4 zz = make_float4(0.f, 0.f, 0.f, 0.f);
#pragma unroll
    for (int c = 0; c < 32; ++c) ((float4*)row)[c * 64 + lane] = zz;
    __builtin_amdgcn_s_waitcnt(0x0F70);   // vmcnt(0): zeros complete before scatter
    if (lane < TOPK) row[myj] = s;
}

// ---------------------------------------------------------------------------
extern "C" void kernel_launch(void* const* d_in, const int* in_sizes, int n_in,
                              void* d_out, int out_size, void* d_ws, size_t ws_size,
                              hipStream_t stream)
{
    const float* X1 = (const float*)d_in[0];
    const float* X2 = (const float*)d_in[1];
    float* out = (float*)d_out;
    float* nrm = (float*)d_ws;                 // 2*N floats = 64 KB

    norms_kernel<<<(2 * N + 255) / 256, 256, 0, stream>>>(X1, X2, nrm);

    dim3 grid(N / TILE, N / TILE);
    dist_kernel<<<grid, 256, 0, stream>>>(X1, X2, nrm, out);

    topk_kernel<<<N / 4, 256, 0, stream>>>(out, out + (size_t)N * N);
}

// Round 3
// 476.874 us; speedup vs baseline: 1.7044x; 1.7044x over previous
//
#include <hip/hip_runtime.h>
#include <math.h>
#include <float.h>
#include <limits.h>

#define N 8192
#define D 64
#define TOPK 32
#define TILE 128
#define CAP 1024

// orderable-uint encoding of float: a > b  <=>  ford(a) > ford(b)
__device__ __forceinline__ unsigned ford(float f) {
    unsigned u = __float_as_uint(f);
    return u ^ ((u & 0x80000000u) ? 0xFFFFFFFFu : 0x80000000u);
}
__device__ __forceinline__ float finv(unsigned u) {
    unsigned b = (u & 0x80000000u) ? (u ^ 0x80000000u) : ~u;
    return __uint_as_float(b);
}

// ---------------------------------------------------------------------------
// Kernel 1: row norms of X1 and X2 -> ws[0..2N)
// ---------------------------------------------------------------------------
__global__ __launch_bounds__(256) void norms_kernel(
    const float* __restrict__ X1, const float* __restrict__ X2,
    float* __restrict__ nrm)
{
    int id = blockIdx.x * blockDim.x + threadIdx.x;
    if (id >= 2 * N) return;
    const float* X = (id < N) ? X1 : X2;
    int r = (id < N) ? id : id - N;
    const float4* p = (const float4*)(X + (size_t)r * D);
    float s = 0.f;
#pragma unroll
    for (int q = 0; q < D / 4; ++q) {
        float4 v = p[q];
        s += v.x * v.x + v.y * v.y + v.z * v.z + v.w * v.w;
    }
    nrm[id] = s;
}

// ---------------------------------------------------------------------------
// Kernel 2: stores  -max(sq,0)  (monotone proxy for -sqrt; sqrt done on the
// 32 selected in topk -> bit-identical final values). Also emits per-row
// tile maxes to ws for topk's threshold. 128x128 tile, 8x8/thread, XOR-swizzle.
// ---------------------------------------------------------------------------
__global__ __launch_bounds__(256, 2) void dist_kernel(
    const float* __restrict__ X1, const float* __restrict__ X2,
    const float* __restrict__ nrm, float* __restrict__ out,
    float* __restrict__ tmax, int have_tmax)
{
    __shared__ float As[D * TILE];
    __shared__ float Bs[D * TILE];

    const int t = threadIdx.x;
    const int row0 = blockIdx.y * TILE;
    const int col0 = blockIdx.x * TILE;

#pragma unroll
    for (int p = 0; p < 8; ++p) {
        int lin = p * 256 + t;
        int r   = lin >> 4;
        int d4  = (lin & 15) << 2;
        int g   = (d4 >> 2) & 7;
        int cb  = r ^ (g << 3);
        float4 a = *(const float4*)(X1 + (size_t)(row0 + r) * D + d4);
        As[(d4 + 0) * TILE + cb] = a.x;
        As[(d4 + 1) * TILE + cb] = a.y;
        As[(d4 + 2) * TILE + cb] = a.z;
        As[(d4 + 3) * TILE + cb] = a.w;
        float4 b = *(const float4*)(X2 + (size_t)(col0 + r) * D + d4);
        Bs[(d4 + 0) * TILE + cb] = b.x;
        Bs[(d4 + 1) * TILE + cb] = b.y;
        Bs[(d4 + 2) * TILE + cb] = b.z;
        Bs[(d4 + 3) * TILE + cb] = b.w;
    }
    __syncthreads();

    const int tx = t & 15;
    const int ty = t >> 4;
    float acc[8][8] = {};

#pragma unroll 8
    for (int k = 0; k < D; ++k) {
        int gk  = (k >> 2) & 7;
        int ab  = k * TILE + ((ty ^ gk) << 3);
        int bb0 = k * TILE + ((4 * tx) ^ (gk << 3));
        float4 a0 = *(const float4*)&As[ab];
        float4 a1 = *(const float4*)&As[ab + 4];
        float4 b0 = *(const float4*)&Bs[bb0];
        float4 b1 = *(const float4*)&Bs[bb0 + 64];
        float av[8] = {a0.x, a0.y, a0.z, a0.w, a1.x, a1.y, a1.z, a1.w};
        float bv[8] = {b0.x, b0.y, b0.z, b0.w, b1.x, b1.y, b1.z, b1.w};
#pragma unroll
        for (int i = 0; i < 8; ++i)
#pragma unroll
            for (int j = 0; j < 8; ++j)
                acc[i][j] += av[i] * bv[j];
    }

    float na[8], nb[8];
#pragma unroll
    for (int i = 0; i < 8; ++i) na[i] = nrm[row0 + 8 * ty + i];
#pragma unroll
    for (int q = 0; q < 4; ++q) {
        nb[q]     = nrm[N + col0 + 4 * tx + q];
        nb[4 + q] = nrm[N + col0 + 64 + 4 * tx + q];
    }

    float rmax[8];
#pragma unroll
    for (int i = 0; i < 8; ++i) rmax[i] = -FLT_MAX;

#pragma unroll
    for (int i = 0; i < 8; ++i) {
        float* po = out + (size_t)(row0 + 8 * ty + i) * N + col0 + 4 * tx;
        float4 o0, o1;
        float* f0 = (float*)&o0;
        float* f1 = (float*)&o1;
#pragma unroll
        for (int q = 0; q < 4; ++q) {
            float s0 = na[i] + nb[q] - 2.0f * acc[i][q];
            f0[q] = -fmaxf(s0, 0.0f);
            float s1 = na[i] + nb[4 + q] - 2.0f * acc[i][4 + q];
            f1[q] = -fmaxf(s1, 0.0f);
            rmax[i] = fmaxf(rmax[i], fmaxf(f0[q], f1[q]));
        }
        *(float4*)po        = o0;
        *(float4*)(po + 64) = o1;
    }

    if (have_tmax) {
#pragma unroll
        for (int i = 0; i < 8; ++i) {
            float mv = rmax[i];
            mv = fmaxf(mv, __shfl_down(mv, 8, 16));
            mv = fmaxf(mv, __shfl_down(mv, 4, 16));
            mv = fmaxf(mv, __shfl_down(mv, 2, 16));
            mv = fmaxf(mv, __shfl_down(mv, 1, 16));
            if (tx == 0)
                tmax[(size_t)(row0 + 8 * ty + i) * 64 + blockIdx.x] = mv;
        }
    }
}

// ---------------------------------------------------------------------------
// Kernel 3: one wave per row, no block barriers, no big register arrays.
// thr = 32nd-largest tile-max (sound; ~44 survivors expected). Compact
// survivors >= thr into per-wave LDS as packed u64 keys, 32x shfl argmax,
// sqrt+softmax on the 32 winners, zero row + scatter.
// ---------------------------------------------------------------------------
__global__ __launch_bounds__(256) void topk_kernel(
    float* __restrict__ out, float* __restrict__ score_out,
    const float* __restrict__ tmax, int have_tmax)
{
    __shared__ unsigned long long cand[4][CAP];   // 32 KB
    __shared__ int scnt[4];

    const int t    = threadIdx.x;
    const int w    = t >> 6;
    const int lane = t & 63;
    const int r    = blockIdx.x * 4 + w;
    float* row = out + (size_t)r * N;
    const float4* row4 = (const float4*)row;

    float thr;
    float lm = -FLT_MAX;   // per-lane max over its 128 values (for fallback)
    if (have_tmax) {
        float tm = tmax[(size_t)r * 64 + lane];
        unsigned km = ford(tm);
        int rk = 0;
#pragma unroll
        for (int l = 0; l < 64; ++l) {
            unsigned o = __shfl(km, l);
            rk += (o > km || (o == km && l < lane)) ? 1 : 0;
        }
        unsigned long long bm = __ballot(rk == 31);
        thr = __shfl(tm, __ffsll(bm) - 1);
    } else {
#pragma unroll 8
        for (int c = 0; c < 32; ++c) {
            float4 x = row4[c * 64 + lane];
            lm = fmaxf(lm, fmaxf(fmaxf(x.x, x.y), fmaxf(x.z, x.w)));
        }
        thr = lm;   // min of per-lane maxes: sound, ~300 survivors
        for (int off = 32; off > 0; off >>= 1)
            thr = fminf(thr, __shfl_xor(thr, off));
    }

    // compact survivors (>= thr); wave-local, order-independent (keys total-order)
    for (int attempt = 0; ; ++attempt) {
        if (lane == 0) scnt[w] = 0;
        __builtin_amdgcn_s_waitcnt(0xC07F);   // lgkmcnt(0)
        for (int c = 0; c < 32; ++c) {
            float4 x = row4[c * 64 + lane];
            float vs[4] = {x.x, x.y, x.z, x.w};
#pragma unroll
            for (int q = 0; q < 4; ++q) {
                float v = vs[q];
                lm = fmaxf(lm, v);
                if (v >= thr) {
                    int p = atomicAdd(&scnt[w], 1);
                    if (p < CAP) {
                        unsigned long long key =
                            ((unsigned long long)ford(v) << 32) |
                            (unsigned)(8191 - (4 * (c * 64 + lane) + q));
                        cand[w][p] = key;
                    }
                }
            }
        }
        __builtin_amdgcn_s_waitcnt(0xC07F);
        if (scnt[w] <= CAP || attempt == 1) break;
        // sound tighten: 16th-smallest lane-max (>=48 lanes' maxes >= it)
        unsigned kml = ford(lm);
        int rk2 = 0;
#pragma unroll
        for (int l = 0; l < 64; ++l) {
            unsigned o = __shfl(kml, l);
            rk2 += (o < kml || (o == kml && l < lane)) ? 1 : 0;
        }
        unsigned long long bm2 = __ballot(rk2 == 15);
        float t2 = __shfl(lm, __ffsll(bm2) - 1);
        thr = fmaxf(thr, t2);
    }
    const int n = min(scnt[w], CAP);

    // 32 x wave argmax straight out of LDS (typically 1 slot/lane)
    unsigned long long mykey = 0ull;
    for (int it = 0; it < TOPK; ++it) {
        unsigned long long b = 0ull; int bp = 0;
        for (int q = lane; q < n; q += 64) {
            unsigned long long kk = cand[w][q];
            if (kk > b) { b = kk; bp = q; }
        }
        for (int off = 32; off > 0; off >>= 1) {
            unsigned long long ob = __shfl_down(b, off);
            int op = __shfl_down(bp, off);
            if (ob > b) { b = ob; bp = op; }
        }
        unsigned long long b0 = __shfl(b, 0);
        int bp0 = __shfl(bp, 0);
        if (lane == it) { mykey = b0; cand[w][bp0] = 0ull; }
    }

    // sqrt + softmax on the 32 winners (rank == lane)
    float myv = 0.f; int myj = 0;
    if (lane < TOPK) {
        float sv = finv((unsigned)(mykey >> 32));   // stored -max(sq,0)
        myv = -sqrtf(-sv);
        myj = 8191 - (int)(mykey & 0xFFFFFFFFu);
    }
    float Mx = __shfl(myv, 0);
    float e = (lane < TOPK) ? expf(myv - Mx) : 0.f;
    float Z = e;
    for (int off = 32; off > 0; off >>= 1) Z += __shfl_xor(Z, off);
    float s = e / Z;
    if (lane < TOPK) score_out[(size_t)r * TOPK + lane] = s;

    // zero the row (reads all consumed), then scatter
    const float4 zz = make_float4(0.f, 0.f, 0.f, 0.f);
#pragma unroll 8
    for (int c = 0; c < 32; ++c) ((float4*)row)[c * 64 + lane] = zz;
    __builtin_amdgcn_s_waitcnt(0x0F70);   // vmcnt(0): zeros before scatter
    if (lane < TOPK) row[myj] = s;
}

// ---------------------------------------------------------------------------
extern "C" void kernel_launch(void* const* d_in, const int* in_sizes, int n_in,
                              void* d_out, int out_size, void* d_ws, size_t ws_size,
                              hipStream_t stream)
{
    const float* X1 = (const float*)d_in[0];
    const float* X2 = (const float*)d_in[1];
    float* out = (float*)d_out;
    float* nrm = (float*)d_ws;                 // 2*N floats
    float* tmax = nrm + 2 * N;                 // N*64 floats (2 MB)
    size_t need = (size_t)(2 * N + (size_t)N * 64) * sizeof(float);
    int have_tmax = (ws_size >= need) ? 1 : 0;

    norms_kernel<<<(2 * N + 255) / 256, 256, 0, stream>>>(X1, X2, nrm);

    dim3 grid(N / TILE, N / TILE);
    dist_kernel<<<grid, 256, 0, stream>>>(X1, X2, nrm, out, tmax, have_tmax);

    topk_kernel<<<N / 4, 256, 0, stream>>>(out, out + (size_t)N * N, tmax, have_tmax);
}